// Round 11
// baseline (105.985 us; speedup 1.0000x reference)
//
#include <hip/hip_runtime.h>
#include <hip/hip_bf16.h>

// RBF kernel layer: out[n][m] = exp(-||x_n - c_m||^2)
// N=16384, M=4096, D=512, fp32 in/out.
// Round 11: r10 persistent dual-bank overlap + r9 LDS-transpose contiguous
// stores, fused INTO the K-loop. 512 blocks (BM=128 x 4 c-blocks of 256),
// 32 K-tiles. Old acc bank drains via a 32KB LDS transpose region T in 4
// chunks/ot: even kk = owner-wave ds_writes (after MFMA2; visibility via
// next phase's lgkmcnt(0) + barrier), odd kk = all-wave read+exp+1KB-
// contiguous stores. Rotation swizzle g^'=(g+row)&63 (r9-proven, b128
// floor both sides). vmcnt: even N=2, odd N=6, V30 N=0, V31 none.

#define NN 16384
#define MM 4096
#define DD 512

typedef float f32x4 __attribute__((ext_vector_type(4)));
typedef long i64x2 __attribute__((ext_vector_type(2)));

__device__ __forceinline__ void async16(const void* g, void* l) {
  __builtin_amdgcn_global_load_lds(
      (const __attribute__((address_space(1))) void*)g,
      (__attribute__((address_space(3))) void*)l, 16, 0, 0);
}

#define MFMA8(a, b, c) __builtin_amdgcn_mfma_f32_16x16x32_fp8_fp8(a, b, c, 0, 0, 0)
#define WAITVM(n) asm volatile("s_waitcnt vmcnt(" #n ")" ::: "memory")
#define LGKM0 asm volatile("s_waitcnt lgkmcnt(0)" ::: "memory")
#define BAR __builtin_amdgcn_s_barrier()
#define GLD4(dst, addr) \
  asm volatile("global_load_dwordx4 %0, %1, off" : "=v"(dst) : "v"(addr))

// ---------------------------------------------------------------------------
// Prep: fp32 row -> fp8 e4m3 (row bytes packed (kt, fq)-major) + exact fp32
// squared norm. One wave per row.
// ---------------------------------------------------------------------------
__global__ __launch_bounds__(256) void prep_fp8(
    const float* __restrict__ x, const float* __restrict__ c,
    unsigned char* __restrict__ x8, unsigned char* __restrict__ c8,
    float* __restrict__ xsq, float* __restrict__ csq) {
  const int w = threadIdx.x >> 6;
  const int lane = threadIdx.x & 63;
  int row = blockIdx.x * 4 + w;
  const float* src = x;
  unsigned char* dst = x8;
  float* sq = xsq;
  if (row >= NN) {
    row -= NN;
    src = c; dst = c8; sq = csq;
    if (row >= MM) return;
  }
  const float* p = src + (size_t)row * DD + lane * 8;
  float4 v0 = *(const float4*)p;
  float4 v1 = *(const float4*)(p + 4);
  float vv[8] = {v0.x, v0.y, v0.z, v0.w, v1.x, v1.y, v1.z, v1.w};
  float s = 0.f;
#pragma unroll
  for (int j = 0; j < 8; ++j) s += vv[j] * vv[j];
  int pk0 = __builtin_amdgcn_cvt_pk_fp8_f32(vv[0], vv[1], 0, false);
  int pk1 = __builtin_amdgcn_cvt_pk_fp8_f32(vv[2], vv[3], 0, false);
  int pk2 = __builtin_amdgcn_cvt_pk_fp8_f32(vv[4], vv[5], 0, false);
  int pk3 = __builtin_amdgcn_cvt_pk_fp8_f32(vv[6], vv[7], 0, false);
  uint2 wrd;
  wrd.x = (unsigned)(pk0 & 0xFFFF) | ((unsigned)pk1 << 16);
  wrd.y = (unsigned)(pk2 & 0xFFFF) | ((unsigned)pk3 << 16);
  const int db = ((lane >> 3) << 6) + ((lane & 3) << 4) + (((lane >> 2) & 1) << 3);
  *(uint2*)(dst + (size_t)row * DD + db) = wrd;
#pragma unroll
  for (int o = 32; o >= 1; o >>= 1) s += __shfl_down(s, o);
  if (lane == 0) sq[row] = s;
}

// ---------------------------------------------------------------------------
// Persistent GEMM. 512 blocks = 128 x-panels x 4 strips; 8 waves; per wave
// 64 x-rows (wr) x 64 c-cols (wc) = 4x4 16x16 frags; A=centroid, B=x.
// LDS 80KB: X[2][128][64B] @0; C[2][256][64B] @16384; T 32KB @49152.
// K staging/swizzle = r6-proven. E path: see header comment.
// ---------------------------------------------------------------------------
__global__ __launch_bounds__(512, 2) void rbf_gemm(
    const unsigned char* __restrict__ x8, const unsigned char* __restrict__ c8,
    const float* __restrict__ xsq, const float* __restrict__ csq,
    float* __restrict__ out) {
  __shared__ __attribute__((aligned(16))) unsigned char smem[81920];

  const int t = threadIdx.x;
  const int w = t >> 6;
  const int lane = t & 63;
  const int fr = lane & 15;
  const int fq = lane >> 4;
  const int wr = w >> 2;
  const int wc = w & 3;

  const int bid = blockIdx.x;
  const int a = bid & 7, qq = bid >> 3;
  const int x0 = ((a << 4) + (qq >> 2)) << 7;
  const int strip = qq & 3;

  // staging addressing (r10): thread t -> row t>>2, inverse-swizzled source
  const int srow = t >> 2;
  const int ssl = ((t & 3) ^ ((t >> 3) & 3)) << 4;
  const unsigned char* gx = x8 + (size_t)(x0 + srow) * DD + ssl;
  const unsigned char* gc = c8 + (size_t)srow * DD + ssl;

#define COFF(v, i)                                                   \
  ((size_t)(((((strip) << 2) + ((v) >> 3)) << 8) + (i) * 128) * DD + \
   ((v) & 7) * 64)

  const int sxor = (fq ^ ((fr >> 1) & 3)) << 4;
  const int rcb = (wc * 64 + fr) * 64 + sxor;
  const int rxb = (wr * 64 + fr) * 64 + sxor;

  f32x4 aA[4][4], aB[4][4];
  f32x4 csTX, csTY, xsE[4];

#define MF4(AN, Q, V)                                                    \
  do {                                                                   \
    _Pragma("unroll") for (int _n = 0; _n < 4; ++_n) {                   \
      f32x4 _c = ((V)&7) == 0 ? (f32x4){0.f, 0.f, 0.f, 0.f} : AN[Q][_n]; \
      _c = MFMA8(cf[_n][0], xq[0], _c);                                  \
      AN[Q][_n] = MFMA8(cf[_n][1], xq[1], _c);                           \
    }                                                                    \
  } while (0)

// owner-wave write of chunk CH of bank AO into T (rotation swizzle)
#define TWRITE(AO, CH)                                                     \
  do {                                                                     \
    _Pragma("unroll") for (int _ms = 0; _ms < 2; ++_ms) {                  \
      const int _rl = _ms * 16 + fr;                                       \
      _Pragma("unroll") for (int _n = 0; _n < 4; ++_n) {                   \
        const int _g = (wc << 4) + (_n << 2) + fq;                         \
        *(f32x4*)((char*)smem + 49152 + _rl * 1024 +                       \
                  (((_g + _rl) & 63) << 4)) = AO[2 * ((CH)&1) + _ms][_n];  \
      }                                                                    \
    }                                                                      \
  } while (0)

// read 4 rows of chunk (into named t0..t3); separate from EXPST
#define TREAD(CH)                                                          \
  t0 = *(const f32x4*)((char*)smem + 49152 + ((w << 2) + 0) * 1024 +       \
                       (((lane + (w << 2) + 0) & 63) << 4));               \
  t1 = *(const f32x4*)((char*)smem + 49152 + ((w << 2) + 1) * 1024 +       \
                       (((lane + (w << 2) + 1) & 63) << 4));               \
  t2 = *(const f32x4*)((char*)smem + 49152 + ((w << 2) + 2) * 1024 +       \
                       (((lane + (w << 2) + 2) & 63) << 4));               \
  t3 = *(const f32x4*)((char*)smem + 49152 + ((w << 2) + 3) * 1024 +       \
                       (((lane + (w << 2) + 3) & 63) << 4));

#define EXPST1(TV, CH, RI, CSU, CPREO)                                        \
  do {                                                                        \
    const float _xn = xsE[CH][RI] * -1.4426950408889634f;                     \
    f32x4 _v;                                                                 \
    _Pragma("unroll") for (int _j = 0; _j < 4; ++_j) {                        \
      float _arg = __builtin_fmaf(                                            \
          TV[_j], 2.8853900817779268f,                                        \
          __builtin_fmaf(CSU[_j], -1.4426950408889634f, _xn));                \
      _v[_j] = fminf(__builtin_exp2f(_arg), 1.0f);                            \
    }                                                                         \
    *(f32x4*)(out + (size_t)(x0 + (CH)*32 + (w << 2) + (RI)) * MM + (CPREO) + \
              (lane << 2)) = _v;                                              \
  } while (0)

#define EXPST4(CH, CSU, CPREO) \
  EXPST1(t0, CH, 0, CSU, CPREO); EXPST1(t1, CH, 1, CSU, CPREO); \
  EXPST1(t2, CH, 2, CSU, CPREO); EXPST1(t3, CH, 3, CSU, CPREO);

// KT: one K-tile. EACT: E active (store old bank). ODD = V&1 (literal).
// CSLD: load CSL = csq cols of output-tile CSOT (per-lane linear).
#define KT(V, AN, AO, EACT, CPREO, CSU, CSLD, CSL, CSOT, DOVM, VMN)           \
  do {                                                                        \
    const char* bX = (const char*)smem + (((V)&1) << 13);                     \
    const char* bC = (const char*)smem + 16384 + (((V)&1) << 14);             \
    char* dXw = (char*)smem + ((((V) + 1) & 1) << 13) + (w << 10);            \
    char* dCw = (char*)smem + 16384 + (((V)&1) << 14) + (w << 10);            \
    i64x2 cf[4], xq;                                                          \
    f32x4 t0, t1, t2, t3;                                                     \
    cf[0] = *(const i64x2*)(bC + rcb);                                        \
    cf[1] = *(const i64x2*)(bC + rcb + 1024);                                 \
    cf[2] = *(const i64x2*)(bC + rcb + 2048);                                 \
    cf[3] = *(const i64x2*)(bC + rcb + 3072);                                 \
    xq = *(const i64x2*)(bX + rxb);                                           \
    if (CSLD)                                                                 \
      GLD4(CSL, csq + ((((strip) << 2) + (CSOT)) << 8) + (lane << 2));        \
    if ((V) + 1 < 32) async16(gx + (((V) + 1) & 7) * 64, dXw);                \
    BAR; LGKM0;                                                               \
    __builtin_amdgcn_s_setprio(1); MF4(AN, 0, V); __builtin_amdgcn_s_setprio(0); \
    BAR;                                                                      \
    xq = *(const i64x2*)(bX + rxb + 1024);                                    \
    if ((V) + 2 < 32) async16(gc + COFF((V) + 2, 0), dCw);                    \
    if ((EACT) && ((V)&1)) { TREAD(((V)&7) >> 1); }                           \
    BAR; LGKM0;                                                               \
    __builtin_amdgcn_s_setprio(1); MF4(AN, 1, V); __builtin_amdgcn_s_setprio(0); \
    if ((EACT) && ((V)&1)) { EXPST4(((V)&7) >> 1, CSU, CPREO); }              \
    BAR;                                                                      \
    xq = *(const i64x2*)(bX + rxb + 2048);                                    \
    if ((V) + 2 < 32) async16(gc + COFF((V) + 2, 1), dCw + 8192);             \
    BAR; LGKM0;                                                               \
    __builtin_amdgcn_s_setprio(1); MF4(AN, 2, V); __builtin_amdgcn_s_setprio(0); \
    if ((EACT) && !((V)&1) && wr == (((V)&7) >> 2)) { TWRITE(AO, ((V)&7) >> 1); } \
    BAR;                                                                      \
    xq = *(const i64x2*)(bX + rxb + 3072);                                    \
    BAR; LGKM0;                                                               \
    __builtin_amdgcn_s_setprio(1); MF4(AN, 3, V); __builtin_amdgcn_s_setprio(0); \
    if (DOVM) WAITVM(VMN);                                                    \
    BAR; __builtin_amdgcn_sched_barrier(0);                                   \
  } while (0)

  const int CP0 = ((strip << 2) + 0) << 8;
  const int CP1 = ((strip << 2) + 1) << 8;
  const int CP2 = ((strip << 2) + 2) << 8;
  const int CP3 = ((strip << 2) + 3) << 8;

  // --- prologue: xsE (4 GLD4, rows fixed per block), then C(0)x2, X(0),
  // C(1)x2. FIFO [xs x4, C00, C01, X0, C10, C11] -> retire X0: vmcnt(2). ---
  {
    const float* xp = xsq + x0 + (w << 2);
    GLD4(xsE[0], xp); GLD4(xsE[1], xp + 32);
    GLD4(xsE[2], xp + 64); GLD4(xsE[3], xp + 96);
  }
  async16(gc + COFF(0, 0), (char*)smem + 16384 + (w << 10));
  async16(gc + COFF(0, 1), (char*)smem + 16384 + 8192 + (w << 10));
  async16(gx, (char*)smem + (w << 10));
  async16(gc + COFF(1, 0), (char*)smem + 32768 + (w << 10));
  async16(gc + COFF(1, 1), (char*)smem + 32768 + 8192 + (w << 10));
  WAITVM(2);
  BAR;
  __builtin_amdgcn_sched_barrier(0);

  // --- 32 K-tiles, fully unrolled ---
  // ot0: fill aA, no E; V6: load csTX = cols CP0
  KT(0, aA, aB, 0, CP0, csTX, 0, csTX, 0, 1, 2);
  KT(1, aA, aB, 0, CP0, csTX, 0, csTX, 0, 1, 2);
  KT(2, aA, aB, 0, CP0, csTX, 0, csTX, 0, 1, 2);
  KT(3, aA, aB, 0, CP0, csTX, 0, csTX, 0, 1, 2);
  KT(4, aA, aB, 0, CP0, csTX, 0, csTX, 0, 1, 2);
  KT(5, aA, aB, 0, CP0, csTX, 0, csTX, 0, 1, 2);
  KT(6, aA, aB, 0, CP0, csTX, 1, csTX, 0, 1, 2);
  KT(7, aA, aB, 0, CP0, csTX, 0, csTX, 0, 1, 2);
  // ot1: fill aB, E(aA -> CP0, csTX); V14: csTY = cols CP1
  KT(8, aB, aA, 1, CP0, csTX, 0, csTY, 1, 1, 2);
  KT(9, aB, aA, 1, CP0, csTX, 0, csTY, 1, 1, 6);
  KT(10, aB, aA, 1, CP0, csTX, 0, csTY, 1, 1, 2);
  KT(11, aB, aA, 1, CP0, csTX, 0, csTY, 1, 1, 6);
  KT(12, aB, aA, 1, CP0, csTX, 0, csTY, 1, 1, 2);
  KT(13, aB, aA, 1, CP0, csTX, 0, csTY, 1, 1, 6);
  KT(14, aB, aA, 1, CP0, csTX, 1, csTY, 1, 1, 2);
  KT(15, aB, aA, 1, CP0, csTX, 0, csTY, 1, 1, 6);
  // ot2: fill aA, E(aB -> CP1, csTY); V22: csTX = cols CP2
  KT(16, aA, aB, 1, CP1, csTY, 0, csTX, 2, 1, 2);
  KT(17, aA, aB, 1, CP1, csTY, 0, csTX, 2, 1, 6);
  KT(18, aA, aB, 1, CP1, csTY, 0, csTX, 2, 1, 2);
  KT(19, aA, aB, 1, CP1, csTY, 0, csTX, 2, 1, 6);
  KT(20, aA, aB, 1, CP1, csTY, 0, csTX, 2, 1, 2);
  KT(21, aA, aB, 1, CP1, csTY, 0, csTX, 2, 1, 6);
  KT(22, aA, aB, 1, CP1, csTY, 1, csTX, 2, 1, 2);
  KT(23, aA, aB, 1, CP1, csTY, 0, csTX, 2, 1, 6);
  // ot3: fill aB, E(aA -> CP2, csTX); V30: csTY = cols CP3, N=0; V31: no vm
  KT(24, aB, aA, 1, CP2, csTX, 0, csTY, 3, 1, 2);
  KT(25, aB, aA, 1, CP2, csTX, 0, csTY, 3, 1, 6);
  KT(26, aB, aA, 1, CP2, csTX, 0, csTY, 3, 1, 2);
  KT(27, aB, aA, 1, CP2, csTX, 0, csTY, 3, 1, 6);
  KT(28, aB, aA, 1, CP2, csTX, 0, csTY, 3, 1, 2);
  KT(29, aB, aA, 1, CP2, csTX, 0, csTY, 3, 1, 6);
  KT(30, aB, aA, 1, CP2, csTX, 1, csTY, 3, 1, 0);
  KT(31, aB, aA, 1, CP2, csTX, 0, csTY, 3, 0, 0);

  // --- tail: E(aB -> CP3, csTY), serial 4 chunks ---
#define TAILC(CH)                                                  \
  do {                                                             \
    BAR;                                                           \
    if (wr == ((CH) >> 1)) { TWRITE(aB, CH); }                     \
    LGKM0;                                                         \
    BAR;                                                           \
    f32x4 t0, t1, t2, t3;                                          \
    TREAD(CH);                                                     \
    LGKM0;                                                         \
    EXPST4(CH, csTY, CP3);                                         \
  } while (0)
  TAILC(0); TAILC(1); TAILC(2); TAILC(3);
#undef TAILC
}

// ---------------------------------------------------------------------------
// Fallback (ws too small): direct tiled fp32 distance kernel.
// ---------------------------------------------------------------------------
__global__ void rbf_naive(const float* __restrict__ x,
                          const float* __restrict__ c,
                          float* __restrict__ out) {
  __shared__ float sx[16][17], sc[16][17];
  const int tx = threadIdx.x, ty = threadIdx.y;
  const int row = blockIdx.y * 16 + ty;
  const int colb = blockIdx.x * 16;
  float d = 0.f;
  for (int k0 = 0; k0 < DD; k0 += 16) {
    sx[ty][tx] = x[(size_t)row * DD + k0 + tx];
    sc[ty][tx] = c[(size_t)(colb + ty) * DD + k0 + tx];
    __syncthreads();
#pragma unroll
    for (int k = 0; k < 16; ++k) {
      float diff = sx[ty][k] - sc[tx][k];
      d += diff * diff;
    }
    __syncthreads();
  }
  out[(size_t)row * MM + colb + tx] = __expf(-d);
}

extern "C" void kernel_launch(void* const* d_in, const int* in_sizes, int n_in,
                              void* d_out, int out_size, void* d_ws,
                              size_t ws_size, hipStream_t stream) {
  const float* x = (const float*)d_in[0];
  const float* c = (const float*)d_in[1];
  float* out = (float*)d_out;

  char* ws = (char*)d_ws;
  unsigned char* x8 = (unsigned char*)ws;
  unsigned char* c8 = x8 + (size_t)NN * DD;
  float* xsq = (float*)(c8 + (size_t)MM * DD);
  float* csq = xsq + NN;
  const size_t need = (size_t)((char*)(csq + MM) - ws);

  if (ws_size < need) {
    dim3 grid(MM / 16, NN / 16), block(16, 16);
    rbf_naive<<<grid, block, 0, stream>>>(x, c, out);
    return;
  }

  prep_fp8<<<(NN + MM) / 4, 256, 0, stream>>>(x, c, x8, c8, xsq, csq);
  rbf_gemm<<<512, 512, 0, stream>>>(x8, c8, xsq, csq, out);
}

// Round 12
// 101.552 us; speedup vs baseline: 1.0437x; 1.0437x over previous
//
#include <hip/hip_runtime.h>
#include <hip/hip_bf16.h>

// RBF kernel layer: out[n][m] = exp(-||x_n - c_m||^2)
// N=16384, M=4096, D=512, fp32 in/out.
// Round 12: r10 persistent dual-bank overlap, restructured:
//  - 2 super-phases of 16 MFMA per K-tile (was 4x8) -> 2 barriers/tile
//    (was 8). Hazard audit: BAR-mid guards C(V+2)-issue vs cf reads (WAR);
//    BAR-end + counted vmcnt guards staging RAW. X(V+1) targets the other
//    X buffer; xq reads of tile V complete before BAR-end(V) while X(V+2)
//    issues after BAR-end(V) -> safe. Store/GLD ops touch no LDS.
//  - stores grouped: odd tiles issue the 4 n-frags of one m-group
//    back-to-back (per row 4x64B consecutive instrs -> L2 line merge),
//    placed between C0 and C1 in the FIFO.
//  - vmcnt table (re-derived): even tiles 2, odd>=9 6, V30 0, V31 none.
//    Even-tile vmcnt(2) retires the previous odd tile's stores (1-tile
//    drain deadline); GLD4 cs loads are FIFO-older than X(V+1) so the
//    same boundary retires them.

#define NN 16384
#define MM 4096
#define DD 512

typedef float f32x4 __attribute__((ext_vector_type(4)));
typedef long i64x2 __attribute__((ext_vector_type(2)));

__device__ __forceinline__ void async16(const void* g, void* l) {
  __builtin_amdgcn_global_load_lds(
      (const __attribute__((address_space(1))) void*)g,
      (__attribute__((address_space(3))) void*)l, 16, 0, 0);
}

#define MFMA8(a, b, c) __builtin_amdgcn_mfma_f32_16x16x32_fp8_fp8(a, b, c, 0, 0, 0)
#define WAITVM(n) asm volatile("s_waitcnt vmcnt(" #n ")" ::: "memory")
#define LGKM0 asm volatile("s_waitcnt lgkmcnt(0)" ::: "memory")
#define BAR __builtin_amdgcn_s_barrier()
#define GLD4(dst, addr) \
  asm volatile("global_load_dwordx4 %0, %1, off" : "=v"(dst) : "v"(addr))
#define GLD1(dst, addr) \
  asm volatile("global_load_dword %0, %1, off" : "=v"(dst) : "v"(addr))

// ---------------------------------------------------------------------------
// Prep: fp32 row -> fp8 e4m3 (row bytes packed (kt, fq)-major) + exact fp32
// squared norm. One wave per row.
// ---------------------------------------------------------------------------
__global__ __launch_bounds__(256) void prep_fp8(
    const float* __restrict__ x, const float* __restrict__ c,
    unsigned char* __restrict__ x8, unsigned char* __restrict__ c8,
    float* __restrict__ xsq, float* __restrict__ csq) {
  const int w = threadIdx.x >> 6;
  const int lane = threadIdx.x & 63;
  int row = blockIdx.x * 4 + w;
  const float* src = x;
  unsigned char* dst = x8;
  float* sq = xsq;
  if (row >= NN) {
    row -= NN;
    src = c; dst = c8; sq = csq;
    if (row >= MM) return;
  }
  const float* p = src + (size_t)row * DD + lane * 8;
  float4 v0 = *(const float4*)p;
  float4 v1 = *(const float4*)(p + 4);
  float vv[8] = {v0.x, v0.y, v0.z, v0.w, v1.x, v1.y, v1.z, v1.w};
  float s = 0.f;
#pragma unroll
  for (int j = 0; j < 8; ++j) s += vv[j] * vv[j];
  int pk0 = __builtin_amdgcn_cvt_pk_fp8_f32(vv[0], vv[1], 0, false);
  int pk1 = __builtin_amdgcn_cvt_pk_fp8_f32(vv[2], vv[3], 0, false);
  int pk2 = __builtin_amdgcn_cvt_pk_fp8_f32(vv[4], vv[5], 0, false);
  int pk3 = __builtin_amdgcn_cvt_pk_fp8_f32(vv[6], vv[7], 0, false);
  uint2 wrd;
  wrd.x = (unsigned)(pk0 & 0xFFFF) | ((unsigned)pk1 << 16);
  wrd.y = (unsigned)(pk2 & 0xFFFF) | ((unsigned)pk3 << 16);
  const int db = ((lane >> 3) << 6) + ((lane & 3) << 4) + (((lane >> 2) & 1) << 3);
  *(uint2*)(dst + (size_t)row * DD + db) = wrd;
#pragma unroll
  for (int o = 32; o >= 1; o >>= 1) s += __shfl_down(s, o);
  if (lane == 0) sq[row] = s;
}

// ---------------------------------------------------------------------------
// Persistent GEMM. 512 blocks = 128 x-panels (BM=128) x 4 strips; 8 waves;
// per wave 64 x-rows (wr) x 64 c-cols (wc) = 4x4 16x16 frags; A=centroid,
// B=x (lane: x-row = fr, c-cols = fq*4+reg). Dual acc banks alternate per
// output tile; old bank exp'd+stored during the next tile's K-loop.
// LDS 48KB: X[2][128][64B] @0; C[2][256][64B] @16384.
// fp8 swizzle (r6-proven): byte = row*64 + 16*(fq ^ ((row>>1)&3)) + ks*8;
// staging = linear LDS dest + inverse-swizzled global source.
// ---------------------------------------------------------------------------
__global__ __launch_bounds__(512, 2) void rbf_gemm(
    const unsigned char* __restrict__ x8, const unsigned char* __restrict__ c8,
    const float* __restrict__ xsq, const float* __restrict__ csq,
    float* __restrict__ out) {
  __shared__ __attribute__((aligned(16))) unsigned char smem[49152];

  const int t = threadIdx.x;
  const int w = t >> 6;
  const int lane = t & 63;
  const int fr = lane & 15;
  const int fq = lane >> 4;
  const int wr = w >> 2;
  const int wc = w & 3;

  const int bid = blockIdx.x;
  const int a = bid & 7, qq = bid >> 3;
  const int x0 = ((a << 4) + (qq >> 2)) << 7;
  const int strip = qq & 3;

  // staging: thread t -> row t>>2, inverse-swizzled 16B source slot
  const int srow = t >> 2;
  const int ssl = ((t & 3) ^ ((t >> 3) & 3)) << 4;
  const unsigned char* gx = x8 + (size_t)(x0 + srow) * DD + ssl;
  const unsigned char* gc = c8 + (size_t)srow * DD + ssl;

#define COFF(v, i)                                                   \
  ((size_t)(((((strip) << 2) + ((v) >> 3)) << 8) + (i) * 128) * DD + \
   ((v) & 7) * 64)

  const int sxor = (fq ^ ((fr >> 1) & 3)) << 4;
  const int rcb = (wc * 64 + fr) * 64 + sxor;
  const int rxb = (wr * 64 + fr) * 64 + sxor;

  f32x4 aA[4][4], aB[4][4];
  f32x4 csX[4], csY[4];
  float xsr[4];

#define MF4(AN, Q, XQ, V)                                                \
  do {                                                                   \
    _Pragma("unroll") for (int _n = 0; _n < 4; ++_n) {                   \
      f32x4 _c = ((V)&7) == 0 ? (f32x4){0.f, 0.f, 0.f, 0.f} : AN[Q][_n]; \
      _c = MFMA8(cf[_n][0], XQ[0], _c);                                  \
      AN[Q][_n] = MFMA8(cf[_n][1], XQ[1], _c);                           \
    }                                                                    \
  } while (0)

// store the 4 n-frags of m-group M of bank AO, back-to-back (line merge)
#define STFRAG4(AO, M, CSU, CPREO)                                          \
  do {                                                                      \
    const float _xn = xsr[M] * -1.4426950408889634f;                        \
    float* _orow =                                                          \
        out + (size_t)(x0 + wr * 64 + (M)*16 + fr) * MM + (CPREO) +         \
        wc * 64 + (fq << 2);                                                \
    _Pragma("unroll") for (int _n = 0; _n < 4; ++_n) {                      \
      f32x4 _v;                                                             \
      _Pragma("unroll") for (int _j = 0; _j < 4; ++_j) {                    \
        float _arg = __builtin_fmaf(                                        \
            AO[M][_n][_j], 2.8853900817779268f,                             \
            __builtin_fmaf(CSU[_n][_j], -1.4426950408889634f, _xn));        \
        _v[_j] = fminf(__builtin_exp2f(_arg), 1.0f);                        \
      }                                                                     \
      *(f32x4*)(_orow + _n * 16) = _v;                                      \
    }                                                                       \
  } while (0)

// KT: one K-tile, 2 super-phases. FIFO per tile: [gld?, X(V+1), C0(V+2),
// st4?, C1(V+2)].
#define KT(V, AN, AO, SEN, CPREO, CSU, CSLD, CSL, CSOT, DOVM, VMN)            \
  do {                                                                       \
    const char* bX = (const char*)smem + (((V)&1) << 13);                    \
    const char* bC = (const char*)smem + 16384 + (((V)&1) << 14);            \
    char* dXw = (char*)smem + ((((V) + 1) & 1) << 13) + (w << 10);           \
    char* dCw = (char*)smem + 16384 + (((V)&1) << 14) + (w << 10);           \
    i64x2 cf[4], xqA, xqB;                                                   \
    cf[0] = *(const i64x2*)(bC + rcb);                                       \
    cf[1] = *(const i64x2*)(bC + rcb + 1024);                                \
    cf[2] = *(const i64x2*)(bC + rcb + 2048);                                \
    cf[3] = *(const i64x2*)(bC + rcb + 3072);                                \
    xqA = *(const i64x2*)(bX + rxb);                                         \
    xqB = *(const i64x2*)(bX + rxb + 1024);                                  \
    if (CSLD) {                                                              \
      const float* _cp =                                                     \
          csq + ((((strip) << 2) + (CSOT)) << 8) + wc * 64 + (fq << 2);      \
      GLD4(CSL[0], _cp); GLD4(CSL[1], _cp + 16);                             \
      GLD4(CSL[2], _cp + 32); GLD4(CSL[3], _cp + 48);                        \
    }                                                                        \
    if ((V) + 1 < 32) async16(gx + (((V) + 1) & 7) * 64, dXw);               \
    LGKM0;                                                                   \
    __builtin_amdgcn_s_setprio(1);                                           \
    MF4(AN, 0, xqA, V);                                                      \
    MF4(AN, 1, xqB, V);                                                      \
    __builtin_amdgcn_s_setprio(0);                                           \
    BAR; /* all waves' cf/xq reads of buf V&1 done -> C(V+2) may write */    \
    xqA = *(const i64x2*)(bX + rxb + 2048);                                  \
    xqB = *(const i64x2*)(bX + rxb + 3072);                                  \
    if ((V) + 2 < 32) async16(gc + COFF((V) + 2, 0), dCw);                   \
    if (SEN) STFRAG4(AO, ((V)&7) >> 1, CSU, CPREO);                          \
    if ((V) + 2 < 32) async16(gc + COFF((V) + 2, 1), dCw + 8192);            \
    LGKM0;                                                                   \
    __builtin_amdgcn_s_setprio(1);                                           \
    MF4(AN, 2, xqA, V);                                                      \
    MF4(AN, 3, xqB, V);                                                      \
    __builtin_amdgcn_s_setprio(0);                                           \
    if (DOVM) WAITVM(VMN);                                                   \
    BAR;                                                                     \
    __builtin_amdgcn_sched_barrier(0);                                       \
  } while (0)

  const int CP0 = ((strip << 2) + 0) << 8;
  const int CP1 = ((strip << 2) + 1) << 8;
  const int CP2 = ((strip << 2) + 2) << 8;
  const int CP3 = ((strip << 2) + 3) << 8;

  // --- prologue: xsr (4 GLD1), then C(0)x2, X(0), C(1)x2.
  // FIFO [xs x4, C00, C01, X0, C10, C11] -> retire X0: vmcnt(2). ---
  {
    const float* xp = xsq + x0 + wr * 64 + fr;
    GLD1(xsr[0], xp); GLD1(xsr[1], xp + 16);
    GLD1(xsr[2], xp + 32); GLD1(xsr[3], xp + 48);
  }
  async16(gc + COFF(0, 0), (char*)smem + 16384 + (w << 10));
  async16(gc + COFF(0, 1), (char*)smem + 16384 + 8192 + (w << 10));
  async16(gx, (char*)smem + (w << 10));
  async16(gc + COFF(1, 0), (char*)smem + 32768 + (w << 10));
  async16(gc + COFF(1, 1), (char*)smem + 32768 + 8192 + (w << 10));
  WAITVM(2);
  BAR;
  __builtin_amdgcn_sched_barrier(0);

  // --- 32 K-tiles, fully unrolled ---
  // ot0: fill aA, no stores; V6: load csX = cols CP0
  KT(0, aA, aB, 0, CP0, csX, 0, csX, 0, 1, 2);
  KT(1, aA, aB, 0, CP0, csX, 0, csX, 0, 1, 2);
  KT(2, aA, aB, 0, CP0, csX, 0, csX, 0, 1, 2);
  KT(3, aA, aB, 0, CP0, csX, 0, csX, 0, 1, 2);
  KT(4, aA, aB, 0, CP0, csX, 0, csX, 0, 1, 2);
  KT(5, aA, aB, 0, CP0, csX, 0, csX, 0, 1, 2);
  KT(6, aA, aB, 0, CP0, csX, 1, csX, 0, 1, 2);
  KT(7, aA, aB, 0, CP0, csX, 0, csX, 0, 1, 2);
  // ot1: fill aB, store aA (cols CP0, csX); V14: load csY = cols CP1
  KT(8, aB, aA, 0, CP0, csX, 0, csY, 1, 1, 2);
  KT(9, aB, aA, 1, CP0, csX, 0, csY, 1, 1, 6);
  KT(10, aB, aA, 0, CP0, csX, 0, csY, 1, 1, 2);
  KT(11, aB, aA, 1, CP0, csX, 0, csY, 1, 1, 6);
  KT(12, aB, aA, 0, CP0, csX, 0, csY, 1, 1, 2);
  KT(13, aB, aA, 1, CP0, csX, 0, csY, 1, 1, 6);
  KT(14, aB, aA, 0, CP0, csX, 1, csY, 1, 1, 2);
  KT(15, aB, aA, 1, CP0, csX, 0, csY, 1, 1, 6);
  // ot2: fill aA, store aB (cols CP1, csY); V22: load csX = cols CP2
  KT(16, aA, aB, 0, CP1, csY, 0, csX, 2, 1, 2);
  KT(17, aA, aB, 1, CP1, csY, 0, csX, 2, 1, 6);
  KT(18, aA, aB, 0, CP1, csY, 0, csX, 2, 1, 2);
  KT(19, aA, aB, 1, CP1, csY, 0, csX, 2, 1, 6);
  KT(20, aA, aB, 0, CP1, csY, 0, csX, 2, 1, 2);
  KT(21, aA, aB, 1, CP1, csY, 0, csX, 2, 1, 6);
  KT(22, aA, aB, 0, CP1, csY, 1, csX, 2, 1, 2);
  KT(23, aA, aB, 1, CP1, csY, 0, csX, 2, 1, 6);
  // ot3: fill aB, store aA (cols CP2, csX); V30: load csY = cols CP3
  KT(24, aB, aA, 0, CP2, csX, 0, csY, 3, 1, 2);
  KT(25, aB, aA, 1, CP2, csX, 0, csY, 3, 1, 6);
  KT(26, aB, aA, 0, CP2, csX, 0, csY, 3, 1, 2);
  KT(27, aB, aA, 1, CP2, csX, 0, csY, 3, 1, 6);
  KT(28, aB, aA, 0, CP2, csX, 0, csY, 3, 1, 2);
  KT(29, aB, aA, 1, CP2, csX, 0, csY, 3, 1, 6);
  KT(30, aB, aA, 0, CP2, csX, 1, csY, 3, 1, 0);
  KT(31, aB, aA, 1, CP2, csX, 0, csY, 3, 0, 0);

  // --- tail: store aB (ot3 results, cols CP3, csY loaded V30) ---
  STFRAG4(aB, 0, csY, CP3);
  STFRAG4(aB, 1, csY, CP3);
  STFRAG4(aB, 2, csY, CP3);
  STFRAG4(aB, 3, csY, CP3);
}

// ---------------------------------------------------------------------------
// Fallback (ws too small): direct tiled fp32 distance kernel.
// ---------------------------------------------------------------------------
__global__ void rbf_naive(const float* __restrict__ x,
                          const float* __restrict__ c,
                          float* __restrict__ out) {
  __shared__ float sx[16][17], sc[16][17];
  const int tx = threadIdx.x, ty = threadIdx.y;
  const int row = blockIdx.y * 16 + ty;
  const int colb = blockIdx.x * 16;
  float d = 0.f;
  for (int k0 = 0; k0 < DD; k0 += 16) {
    sx[ty][tx] = x[(size_t)row * DD + k0 + tx];
    sc[ty][tx] = c[(size_t)(colb + ty) * DD + k0 + tx];
    __syncthreads();
#pragma unroll
    for (int k = 0; k < 16; ++k) {
      float diff = sx[ty][k] - sc[tx][k];
      d += diff * diff;
    }
    __syncthreads();
  }
  out[(size_t)row * MM + colb + tx] = __expf(-d);
}

extern "C" void kernel_launch(void* const* d_in, const int* in_sizes, int n_in,
                              void* d_out, int out_size, void* d_ws,
                              size_t ws_size, hipStream_t stream) {
  const float* x = (const float*)d_in[0];
  const float* c = (const float*)d_in[1];
  float* out = (float*)d_out;

  char* ws = (char*)d_ws;
  unsigned char* x8 = (unsigned char*)ws;
  unsigned char* c8 = x8 + (size_t)NN * DD;
  float* xsq = (float*)(c8 + (size_t)MM * DD);
  float* csq = xsq + NN;
  const size_t need = (size_t)((char*)(csq + MM) - ws);

  if (ws_size < need) {
    dim3 grid(MM / 16, NN / 16), block(16, 16);
    rbf_naive<<<grid, block, 0, stream>>>(x, c, out);
    return;
  }

  prep_fp8<<<(NN + MM) / 4, 256, 0, stream>>>(x, c, x8, c8, xsq, csq);
  rbf_gemm<<<512, 512, 0, stream>>>(x8, c8, xsq, csq, out);
}

// Round 14
// 93.170 us; speedup vs baseline: 1.1375x; 1.0900x over previous
//
#include <hip/hip_runtime.h>
#include <hip/hip_bf16.h>

// RBF kernel layer: out[n][m] = exp(-||x_n - c_m||^2)
// N=16384, M=4096, D=512, fp32 in/out.
// Round 14: r13 (BK=128 persistent dual-bank fp8 GEMM) with the correctness
// repair: r13's LDS reads went through pointer->size_t->pointer casts (for
// an ^64 address trick), which can defeat addrspace(3) inference -> flat
// loads -> flat counts in BOTH vmcnt and lgkmcnt -> every counted WAITVM(N)
// wrong -> reads of unstaged LDS -> fp8 0xFF = NaN -> absmax 1.0. Fix:
// direct typed derefs + explicit second slot offset sxb (no int round-trip,
// no XOR on addresses). Schedule/staging/swizzle identical to r13:
//
// LDS 96KB: X[2][128][128B] @0/16384; C[2][256][128B] @32768/65536.
// Swizzle: LDS[row][slot] holds global 16B chunk g = slot ^ (row&7);
// read chunk fq at slot fq^(fr&7) (sxa), chunk fq|4 at (fq|4)^(fr&7) (sxb).
// Staging: linear dest (thread t -> row t>>3, slot t&7), source chunk
// (t&7)^((t>>3)&7).
// FIFO per tile V: [cs?x4, X(V+1)x2, C(V+2)x4, STx4]; boundary vmcnt:
// V0-3: 4; V4-13: 8; V14: 4; V15: none. Prologue [xs4, C0x4, X0x2, C1x4]
// -> vmcnt(4). acc banks alternate per ot; stores of old bank m-group V&3.

#define NN 16384
#define MM 4096
#define DD 512

typedef float f32x4 __attribute__((ext_vector_type(4)));
typedef long i64x2 __attribute__((ext_vector_type(2)));

__device__ __forceinline__ void async16(const void* g, void* l) {
  __builtin_amdgcn_global_load_lds(
      (const __attribute__((address_space(1))) void*)g,
      (__attribute__((address_space(3))) void*)l, 16, 0, 0);
}

#define MFMA8(a, b, c) __builtin_amdgcn_mfma_f32_16x16x32_fp8_fp8(a, b, c, 0, 0, 0)
#define WAITVM(n) asm volatile("s_waitcnt vmcnt(" #n ")" ::: "memory")
#define LGKM0 asm volatile("s_waitcnt lgkmcnt(0)" ::: "memory")
#define BAR __builtin_amdgcn_s_barrier()
#define GLD4(dst, addr) \
  asm volatile("global_load_dwordx4 %0, %1, off" : "=v"(dst) : "v"(addr))
#define GLD1(dst, addr) \
  asm volatile("global_load_dword %0, %1, off" : "=v"(dst) : "v"(addr))

// ---------------------------------------------------------------------------
// Prep: fp32 row -> fp8 e4m3 (row bytes packed (kt, fq)-major: byte =
// kt*64 + fq*16 + ks*8 + e for element k = kt*64 + ks*32 + fq*8 + e) +
// exact fp32 squared norm. One wave per row.
// ---------------------------------------------------------------------------
__global__ __launch_bounds__(256) void prep_fp8(
    const float* __restrict__ x, const float* __restrict__ c,
    unsigned char* __restrict__ x8, unsigned char* __restrict__ c8,
    float* __restrict__ xsq, float* __restrict__ csq) {
  const int w = threadIdx.x >> 6;
  const int lane = threadIdx.x & 63;
  int row = blockIdx.x * 4 + w;
  const float* src = x;
  unsigned char* dst = x8;
  float* sq = xsq;
  if (row >= NN) {
    row -= NN;
    src = c; dst = c8; sq = csq;
    if (row >= MM) return;
  }
  const float* p = src + (size_t)row * DD + lane * 8;
  float4 v0 = *(const float4*)p;
  float4 v1 = *(const float4*)(p + 4);
  float vv[8] = {v0.x, v0.y, v0.z, v0.w, v1.x, v1.y, v1.z, v1.w};
  float s = 0.f;
#pragma unroll
  for (int j = 0; j < 8; ++j) s += vv[j] * vv[j];
  int pk0 = __builtin_amdgcn_cvt_pk_fp8_f32(vv[0], vv[1], 0, false);
  int pk1 = __builtin_amdgcn_cvt_pk_fp8_f32(vv[2], vv[3], 0, false);
  int pk2 = __builtin_amdgcn_cvt_pk_fp8_f32(vv[4], vv[5], 0, false);
  int pk3 = __builtin_amdgcn_cvt_pk_fp8_f32(vv[6], vv[7], 0, false);
  uint2 wrd;
  wrd.x = (unsigned)(pk0 & 0xFFFF) | ((unsigned)pk1 << 16);
  wrd.y = (unsigned)(pk2 & 0xFFFF) | ((unsigned)pk3 << 16);
  const int db = ((lane >> 3) << 6) + ((lane & 3) << 4) + (((lane >> 2) & 1) << 3);
  *(uint2*)(dst + (size_t)row * DD + db) = wrd;
#pragma unroll
  for (int o = 32; o >= 1; o >>= 1) s += __shfl_down(s, o);
  if (lane == 0) sq[row] = s;
}

// ---------------------------------------------------------------------------
// Persistent GEMM. 512 blocks = 128 x-panels (BM=128) x 4 strips; 8 waves;
// per wave 64 x-rows (wr) x 64 c-cols (wc) = 4x4 16x16 frags; A=centroid,
// B=x (lane: x-row = fr, c-cols = fq*4+reg).
// ---------------------------------------------------------------------------
__global__ __launch_bounds__(512, 1) void rbf_gemm(
    const unsigned char* __restrict__ x8, const unsigned char* __restrict__ c8,
    const float* __restrict__ xsq, const float* __restrict__ csq,
    float* __restrict__ out) {
  __shared__ __attribute__((aligned(16))) unsigned char smem[98304];

  const int t = threadIdx.x;
  const int w = t >> 6;
  const int lane = t & 63;
  const int fr = lane & 15;
  const int fq = lane >> 4;
  const int wr = w >> 2;
  const int wc = w & 3;

  const int bid = blockIdx.x;
  const int a = bid & 7, qq = bid >> 3;
  const int x0 = ((a << 4) + (qq >> 2)) << 7;
  const int strip = qq & 3;

  // staging: thread t -> row t>>3 of 64-row issue, inverse-swizzled slot
  const int srow = t >> 3;
  const int ssl = ((t & 7) ^ ((t >> 3) & 7)) << 4;
  const unsigned char* gx = x8 + (size_t)(x0 + srow) * DD + ssl;
  const unsigned char* gc = c8 + (size_t)srow * DD + ssl;

#define XOFF(v, i) ((size_t)(i)*64 * DD + ((v)&3) * 128)
#define COFF(v, i)                                                   \
  ((size_t)(((((strip) << 2) + ((v) >> 2)) << 8) + (i)*64) * DD +    \
   ((v)&3) * 128)

  // ds_read slot offsets: chunk fq (kt0) at sxa, chunk fq|4 (kt1) at sxb
  const int sxa = (fq ^ (fr & 7)) << 4;
  const int sxb = ((fq | 4) ^ (fr & 7)) << 4;
  const int rowC = (wc * 64 + fr) * 128;
  const int rowX = (wr * 64 + fr) * 128;
  const int rcb = rowC + sxa, rcbB = rowC + sxb;   // + n*2048
  const int rxb = rowX + sxa, rxbB = rowX + sxb;   // + m*2048

  f32x4 aA[4][4], aB[4][4];
  f32x4 csX[4], csY[4];
  float xsr[4];

#define RD(base, off) (*(const i64x2*)((base) + (off)))

// one m-group: 4 n x 4 k-slices = 16 MFMAs. Zero-init acc at ot start.
#define MF16(AN, M, XA, XB, V)                                            \
  do {                                                                    \
    _Pragma("unroll") for (int _n = 0; _n < 4; ++_n) {                    \
      f32x4 _c = ((V)&3) == 0 ? (f32x4){0.f, 0.f, 0.f, 0.f} : AN[M][_n];  \
      _c = MFMA8(cfA[_n][0], XA[0], _c);                                  \
      _c = MFMA8(cfA[_n][1], XA[1], _c);                                  \
      _c = MFMA8(cfB[_n][0], XB[0], _c);                                  \
      AN[M][_n] = MFMA8(cfB[_n][1], XB[1], _c);                           \
    }                                                                     \
  } while (0)

// grouped store: 4 n-frags of m-group M, back-to-back (line merge)
#define STFRAG4(AO, M, CSU, CPREO)                                          \
  do {                                                                      \
    const float _xn = xsr[M] * -1.4426950408889634f;                        \
    float* _orow =                                                          \
        out + (size_t)(x0 + wr * 64 + (M)*16 + fr) * MM + (CPREO) +         \
        wc * 64 + (fq << 2);                                                \
    _Pragma("unroll") for (int _n = 0; _n < 4; ++_n) {                      \
      f32x4 _v;                                                             \
      _Pragma("unroll") for (int _j = 0; _j < 4; ++_j) {                    \
        float _arg = __builtin_fmaf(                                        \
            AO[M][_n][_j], 2.8853900817779268f,                             \
            __builtin_fmaf(CSU[_n][_j], -1.4426950408889634f, _xn));        \
        _v[_j] = fminf(__builtin_exp2f(_arg), 1.0f);                        \
      }                                                                     \
      *(f32x4*)(_orow + _n * 16) = _v;                                      \
    }                                                                       \
  } while (0)

#define KT(V, AN, AO, SEN, CPREO, CSU, CSLD, CSL, CSOT, DOVM, VMN)            \
  do {                                                                       \
    const char* bX = (const char*)smem + (((V)&1) << 14);                    \
    const char* bC = (const char*)smem + 32768 + (((V)&1) << 15);            \
    char* dX = (char*)smem + ((((V) + 1) & 1) << 14) + (w << 10);            \
    char* dC = (char*)smem + 32768 + (((V)&1) << 15) + (w << 10);            \
    i64x2 cfA[4], cfB[4], xA0, xB0, xA1, xB1;                                \
    if (CSLD) {                                                              \
      const float* _cp =                                                     \
          csq + ((((strip) << 2) + (CSOT)) << 8) + wc * 64 + (fq << 2);      \
      GLD4(CSL[0], _cp); GLD4(CSL[1], _cp + 16);                             \
      GLD4(CSL[2], _cp + 32); GLD4(CSL[3], _cp + 48);                        \
    }                                                                        \
    cfA[0] = RD(bC, rcb);          cfB[0] = RD(bC, rcbB);                    \
    cfA[1] = RD(bC, rcb + 2048);   cfB[1] = RD(bC, rcbB + 2048);             \
    cfA[2] = RD(bC, rcb + 4096);   cfB[2] = RD(bC, rcbB + 4096);             \
    cfA[3] = RD(bC, rcb + 6144);   cfB[3] = RD(bC, rcbB + 6144);             \
    xA0 = RD(bX, rxb);             xB0 = RD(bX, rxbB);                       \
    xA1 = RD(bX, rxb + 2048);      xB1 = RD(bX, rxbB + 2048);                \
    if ((V) + 1 < 16) {                                                      \
      async16(gx + XOFF((V) + 1, 0), dX);                                    \
      async16(gx + XOFF((V) + 1, 1), dX + 8192);                             \
    }                                                                        \
    LGKM0;                                                                   \
    __builtin_amdgcn_s_setprio(1);                                           \
    MF16(AN, 0, xA0, xB0, V);                                                \
    MF16(AN, 1, xA1, xB1, V);                                                \
    __builtin_amdgcn_s_setprio(0);                                           \
    BAR; /* all waves' cf reads of buf V&1 done -> C(V+2) may overwrite */   \
    xA0 = RD(bX, rxb + 4096);      xB0 = RD(bX, rxbB + 4096);                \
    xA1 = RD(bX, rxb + 6144);      xB1 = RD(bX, rxbB + 6144);                \
    if ((V) + 2 < 16) {                                                      \
      async16(gc + COFF((V) + 2, 0), dC);                                    \
      async16(gc + COFF((V) + 2, 1), dC + 8192);                             \
      async16(gc + COFF((V) + 2, 2), dC + 16384);                            \
      async16(gc + COFF((V) + 2, 3), dC + 24576);                            \
    }                                                                        \
    if (SEN) STFRAG4(AO, (V)&3, CSU, CPREO);                                 \
    LGKM0;                                                                   \
    __builtin_amdgcn_s_setprio(1);                                           \
    MF16(AN, 2, xA0, xB0, V);                                                \
    MF16(AN, 3, xA1, xB1, V);                                                \
    __builtin_amdgcn_s_setprio(0);                                           \
    if (DOVM) WAITVM(VMN);                                                   \
    BAR;                                                                     \
    __builtin_amdgcn_sched_barrier(0);                                       \
  } while (0)

  const int CP0 = ((strip << 2) + 0) << 8;
  const int CP1 = ((strip << 2) + 1) << 8;
  const int CP2 = ((strip << 2) + 2) << 8;
  const int CP3 = ((strip << 2) + 3) << 8;

  // --- prologue: xsr, C(0)x4 -> Cbuf0, X(0)x2 -> Xbuf0, C(1)x4 -> Cbuf1.
  // FIFO [xs4, C0x4, X0x2, C1x4] -> retire X0: vmcnt(4). ---
  {
    const float* xp = xsq + x0 + wr * 64 + fr;
    GLD1(xsr[0], xp); GLD1(xsr[1], xp + 16);
    GLD1(xsr[2], xp + 32); GLD1(xsr[3], xp + 48);
  }
  async16(gc + COFF(0, 0), (char*)smem + 32768 + (w << 10));
  async16(gc + COFF(0, 1), (char*)smem + 32768 + 8192 + (w << 10));
  async16(gc + COFF(0, 2), (char*)smem + 32768 + 16384 + (w << 10));
  async16(gc + COFF(0, 3), (char*)smem + 32768 + 24576 + (w << 10));
  async16(gx + XOFF(0, 0), (char*)smem + (w << 10));
  async16(gx + XOFF(0, 1), (char*)smem + 8192 + (w << 10));
  async16(gc + COFF(1, 0), (char*)smem + 65536 + (w << 10));
  async16(gc + COFF(1, 1), (char*)smem + 65536 + 8192 + (w << 10));
  async16(gc + COFF(1, 2), (char*)smem + 65536 + 16384 + (w << 10));
  async16(gc + COFF(1, 3), (char*)smem + 65536 + 24576 + (w << 10));
  WAITVM(4);
  BAR;
  __builtin_amdgcn_sched_barrier(0);

  // --- 16 K-tiles, fully unrolled ---
  // ot0 (V0-3): fill aA, no stores; V2: csX <- CP0
  KT(0, aA, aB, 0, CP0, csX, 0, csX, 0, 1, 4);
  KT(1, aA, aB, 0, CP0, csX, 0, csX, 0, 1, 4);
  KT(2, aA, aB, 0, CP0, csX, 1, csX, 0, 1, 4);
  KT(3, aA, aB, 0, CP0, csX, 0, csX, 0, 1, 4);
  // ot1 (V4-7): fill aB, store aA (CP0, csX); V6: csY <- CP1
  KT(4, aB, aA, 1, CP0, csX, 0, csY, 1, 1, 8);
  KT(5, aB, aA, 1, CP0, csX, 0, csY, 1, 1, 8);
  KT(6, aB, aA, 1, CP0, csX, 1, csY, 1, 1, 8);
  KT(7, aB, aA, 1, CP0, csX, 0, csY, 1, 1, 8);
  // ot2 (V8-11): fill aA, store aB (CP1, csY); V10: csX <- CP2
  KT(8, aA, aB, 1, CP1, csY, 0, csX, 2, 1, 8);
  KT(9, aA, aB, 1, CP1, csY, 0, csX, 2, 1, 8);
  KT(10, aA, aB, 1, CP1, csY, 1, csX, 2, 1, 8);
  KT(11, aA, aB, 1, CP1, csY, 0, csX, 2, 1, 8);
  // ot3 (V12-15): fill aB, store aA (CP2, csX); V14: csY <- CP3
  KT(12, aB, aA, 1, CP2, csX, 0, csY, 3, 1, 8);
  KT(13, aB, aA, 1, CP2, csX, 0, csY, 3, 1, 8);
  KT(14, aB, aA, 1, CP2, csX, 1, csY, 3, 1, 4);
  KT(15, aB, aA, 1, CP2, csX, 0, csY, 3, 0, 0);

  // --- tail: store aB (ot3 results, CP3, csY) ---
  STFRAG4(aB, 0, csY, CP3);
  STFRAG4(aB, 1, csY, CP3);
  STFRAG4(aB, 2, csY, CP3);
  STFRAG4(aB, 3, csY, CP3);
}

// ---------------------------------------------------------------------------
// Fallback (ws too small): direct tiled fp32 distance kernel.
// ---------------------------------------------------------------------------
__global__ void rbf_naive(const float* __restrict__ x,
                          const float* __restrict__ c,
                          float* __restrict__ out) {
  __shared__ float sx[16][17], sc[16][17];
  const int tx = threadIdx.x, ty = threadIdx.y;
  const int row = blockIdx.y * 16 + ty;
  const int colb = blockIdx.x * 16;
  float d = 0.f;
  for (int k0 = 0; k0 < DD; k0 += 16) {
    sx[ty][tx] = x[(size_t)row * DD + k0 + tx];
    sc[ty][tx] = c[(size_t)(colb + ty) * DD + k0 + tx];
    __syncthreads();
#pragma unroll
    for (int k = 0; k < 16; ++k) {
      float diff = sx[ty][k] - sc[tx][k];
      d += diff * diff;
    }
    __syncthreads();
  }
  out[(size_t)row * MM + colb + tx] = __expf(-d);
}

extern "C" void kernel_launch(void* const* d_in, const int* in_sizes, int n_in,
                              void* d_out, int out_size, void* d_ws,
                              size_t ws_size, hipStream_t stream) {
  const float* x = (const float*)d_in[0];
  const float* c = (const float*)d_in[1];
  float* out = (float*)d_out;

  char* ws = (char*)d_ws;
  unsigned char* x8 = (unsigned char*)ws;
  unsigned char* c8 = x8 + (size_t)NN * DD;
  float* xsq = (float*)(c8 + (size_t)MM * DD);
  float* csq = xsq + NN;
  const size_t need = (size_t)((char*)(csq + MM) - ws);

  if (ws_size < need) {
    dim3 grid(MM / 16, NN / 16), block(16, 16);
    rbf_naive<<<grid, block, 0, stream>>>(x, c, out);
    return;
  }

  prep_fp8<<<(NN + MM) / 4, 256, 0, stream>>>(x, c, x8, c8, xsq, csq);
  rbf_gemm<<<512, 512, 0, stream>>>(x8, c8, xsq, csq, out);
}